// Round 5
// baseline (127.827 us; speedup 1.0000x reference)
//
#include <hip/hip_runtime.h>
#include <hip/hip_bf16.h>

#define TT 8192
#define DIN 512
#define DQK 64

typedef __attribute__((ext_vector_type(8))) short short8;
typedef __attribute__((ext_vector_type(4))) float f32x4;

// ---------------- zero kernel ----------------
__global__ __launch_bounds__(256) void zero_kernel(float* __restrict__ out, int n4)
{
    int i = blockIdx.x * 256 + threadIdx.x;
    if (i < n4) ((f32x4*)out)[i] = (f32x4){0.f, 0.f, 0.f, 0.f};
}

// ---------------- Kernel 0: W [512][64] f32 -> WT bf16 [3][64][512] ----------------
__global__ __launch_bounds__(256) void wconv_kernel(
    const float* __restrict__ Wq, const float* __restrict__ Wk, const float* __restrict__ Wv,
    __hip_bfloat16* __restrict__ wtb)
{
    __shared__ float tile[64][65];
    const int m = blockIdx.y;
    const float* W = m == 0 ? Wq : (m == 1 ? Wk : Wv);
    const int k0 = blockIdx.x * 64;
    const int tid = threadIdx.x;

    {
        const int col4 = (tid & 15) * 4;
        #pragma unroll
        for (int it = 0; it < 4; ++it) {
            const int row = (tid >> 4) + it * 16;
            float4 v = *(const float4*)&W[(size_t)(k0 + row) * DQK + col4];
            tile[row][col4 + 0] = v.x; tile[row][col4 + 1] = v.y;
            tile[row][col4 + 2] = v.z; tile[row][col4 + 3] = v.w;
        }
    }
    __syncthreads();
    {
        const int d = tid >> 2;
        const int kc = (tid & 3) * 16;
        short tmp[16];
        #pragma unroll
        for (int j = 0; j < 16; ++j) {
            __hip_bfloat16 h = __float2bfloat16(tile[kc + j][d]);
            tmp[j] = *(short*)&h;
        }
        short* dst = (short*)wtb + ((size_t)m * 64 + d) * DIN + k0 + kc;
        *(short8*)dst       = *(short8*)&tmp[0];
        *(short8*)(dst + 8) = *(short8*)&tmp[8];
    }
}

// ---------------- Kernel 1: MFMA projections ----------------
#define PP 72

__global__ __launch_bounds__(256) void proj_kernel(
    const float* __restrict__ x,
    const __hip_bfloat16* __restrict__ wtb,
    __hip_bfloat16* __restrict__ qb, __hip_bfloat16* __restrict__ kb,
    __hip_bfloat16* __restrict__ vt)
{
    __shared__ short xb[64][PP];        // x tile [row][k]
    __shared__ short wb[3][64][PP];     // W^T tiles [m][col(d)][k]

    const int rowBase = blockIdx.x * 64;
    const int tid = threadIdx.x;
    const int lane = tid & 63;
    const int w = tid >> 6;
    const int lo = lane & 15, hi = lane >> 4;

    f32x4 acc[3][4];
    #pragma unroll
    for (int m = 0; m < 3; ++m)
        #pragma unroll
        for (int cf = 0; cf < 4; ++cf) acc[m][cf] = (f32x4){0.f, 0.f, 0.f, 0.f};

    for (int kk = 0; kk < DIN; kk += 64) {
        // stage x 64x64 -> bf16 (vectorized)
        {
            const int r = tid >> 2;
            const int c0 = (tid & 3) * 16;
            const float* xp = x + (size_t)(rowBase + r) * DIN + kk + c0;
            short tmp[16];
            #pragma unroll
            for (int j = 0; j < 16; j += 4) {
                float4 v = *(const float4*)(xp + j);
                __hip_bfloat16 h0 = __float2bfloat16(v.x);
                __hip_bfloat16 h1 = __float2bfloat16(v.y);
                __hip_bfloat16 h2 = __float2bfloat16(v.z);
                __hip_bfloat16 h3 = __float2bfloat16(v.w);
                tmp[j + 0] = *(short*)&h0; tmp[j + 1] = *(short*)&h1;
                tmp[j + 2] = *(short*)&h2; tmp[j + 3] = *(short*)&h3;
            }
            *(short8*)&xb[r][c0]     = *(short8*)&tmp[0];
            *(short8*)&xb[r][c0 + 8] = *(short8*)&tmp[8];
        }
        // stage W^T (already bf16, vector copy)
        {
            const int d = tid >> 2;
            const int kc = (tid & 3) * 16;
            #pragma unroll
            for (int m = 0; m < 3; ++m) {
                const short* src = (const short*)wtb + ((size_t)m * 64 + d) * DIN + kk + kc;
                *(short8*)&wb[m][d][kc]     = *(const short8*)src;
                *(short8*)&wb[m][d][kc + 8] = *(const short8*)(src + 8);
            }
        }
        __syncthreads();

        short8 a0 = *(short8*)&xb[w * 16 + lo][hi * 8];
        short8 a1 = *(short8*)&xb[w * 16 + lo][32 + hi * 8];
        #pragma unroll
        for (int m = 0; m < 3; ++m) {
            #pragma unroll
            for (int cf = 0; cf < 4; ++cf) {
                short8 b0 = *(short8*)&wb[m][cf * 16 + lo][hi * 8];
                short8 b1 = *(short8*)&wb[m][cf * 16 + lo][32 + hi * 8];
                acc[m][cf] = __builtin_amdgcn_mfma_f32_16x16x32_bf16(a0, b0, acc[m][cf], 0, 0, 0);
                acc[m][cf] = __builtin_amdgcn_mfma_f32_16x16x32_bf16(a1, b1, acc[m][cf], 0, 0, 0);
            }
        }
        __syncthreads();
    }

    #pragma unroll
    for (int cf = 0; cf < 4; ++cf) {
        #pragma unroll
        for (int r = 0; r < 4; ++r) {
            const int tg = rowBase + w * 16 + hi * 4 + r;
            const int d  = cf * 16 + lo;
            __hip_bfloat16 hq = __float2bfloat16(acc[0][cf][r]);
            __hip_bfloat16 hk = __float2bfloat16(acc[1][cf][r]);
            __hip_bfloat16 hv = __float2bfloat16(acc[2][cf][r]);
            qb[(size_t)tg * DQK + d] = hq;
            kb[(size_t)tg * DQK + d] = hk;
            vt[(size_t)d * TT + tg]  = hv;
        }
    }
}

// ---------------- Kernel 2: barrier-free MFMA triangular core ----------------
#define TM 128       // t rows per block (8 waves x 16)
#define TS 64        // s per step
#define SCHUNK 256   // s range per block (grid.y)

__global__ __launch_bounds__(512) void attn_kernel(
    const __hip_bfloat16* __restrict__ qb,
    const __hip_bfloat16* __restrict__ kb,
    const __hip_bfloat16* __restrict__ vt,
    const float* __restrict__ l,
    float* __restrict__ out)
{
    // ONLY wave-private LDS (S layout bounce). No __syncthreads anywhere.
    __shared__ short S_lds[8][16][72];

    const int t0 = blockIdx.x * TM;
    const int sStart = blockIdx.y * SCHUNK;
    if (sStart >= t0 + TM) return;
    const int sEnd = min(sStart + SCHUNK, t0 + TM);

    const int tid = threadIdx.x;
    const int lane = tid & 63;
    const int w = tid >> 6;
    const int lo = lane & 15, hi = lane >> 4;
    const int trow = t0 + w * 16;

    // wave-uniform active range: steps with s0 <= trow+15 form a prefix
    const int myEnd = min(sEnd, trow + 16);
    if (myEnd <= sStart) return;   // wave-uniform exit; no barriers in kernel

    short8 qf0, qf1;
    {
        const short* qp = (const short*)qb + (size_t)(trow + lo) * DQK;
        qf0 = *(const short8*)(qp + hi * 8);
        qf1 = *(const short8*)(qp + 32 + hi * 8);
    }

    f32x4 acc_o[4];
    #pragma unroll
    for (int i = 0; i < 4; ++i) acc_o[i] = (f32x4){0.f, 0.f, 0.f, 0.f};

    const int r0 = hi * 4;                // C-row base within 16-row slab

    // l register double-buffer; with no barriers the in-flight loads survive
    float lvC[4][4];
    float lvN[4][4];
    #pragma unroll
    for (int sub = 0; sub < 4; ++sub) {
        const int s_glob = sStart + sub * 16 + lo;
        #pragma unroll
        for (int r = 0; r < 4; ++r) {
            const int tg = trow + r0 + r;
            lvC[sub][r] = (s_glob <= tg) ? l[(size_t)tg * TT + s_glob] : 0.f;
        }
    }

    for (int s0 = sStart; s0 < myEnd; s0 += TS) {
        const int sN = s0 + TS;
        const bool pf = (sN < myEnd);

        // prefetch next step's l slice (stays in flight through this step)
        #pragma unroll
        for (int sub = 0; sub < 4; ++sub) {
            const int s_glob = sN + sub * 16 + lo;
            #pragma unroll
            for (int r = 0; r < 4; ++r) {
                const int tg = trow + r0 + r;
                lvN[sub][r] = (pf && s_glob <= tg) ? l[(size_t)tg * TT + s_glob] : 0.f;
            }
        }

        // QK^T: K fragments straight from global (L1/L2-resident, 64B segments)
        const short* kbase = (const short*)kb + (size_t)s0 * DQK;
        #pragma unroll
        for (int sub = 0; sub < 4; ++sub) {
            const short* krow = kbase + (size_t)(sub * 16 + lo) * DQK;
            short8 b0 = *(const short8*)(krow + hi * 8);
            short8 b1 = *(const short8*)(krow + 32 + hi * 8);
            f32x4 acc = (f32x4){0.f, 0.f, 0.f, 0.f};
            acc = __builtin_amdgcn_mfma_f32_16x16x32_bf16(qf0, b0, acc, 0, 0, 0);
            acc = __builtin_amdgcn_mfma_f32_16x16x32_bf16(qf1, b1, acc, 0, 0, 0);
            #pragma unroll
            for (int r = 0; r < 4; ++r) {
                float sv = acc[r] * lvC[sub][r];
                __hip_bfloat16 h = __float2bfloat16(sv);
                S_lds[w][r0 + r][sub * 16 + lo] = *(short*)&h;
            }
        }

        // PV: S from wave-private LDS, V fragments straight from global
        short8 a0 = *(short8*)&S_lds[w][lo][hi * 8];
        short8 a1 = *(short8*)&S_lds[w][lo][32 + hi * 8];
        #pragma unroll
        for (int ds = 0; ds < 4; ++ds) {
            const short* vrow = (const short*)vt + (size_t)(ds * 16 + lo) * TT + s0;
            short8 b0 = *(const short8*)(vrow + hi * 8);
            short8 b1 = *(const short8*)(vrow + 32 + hi * 8);
            acc_o[ds] = __builtin_amdgcn_mfma_f32_16x16x32_bf16(a0, b0, acc_o[ds], 0, 0, 0);
            acc_o[ds] = __builtin_amdgcn_mfma_f32_16x16x32_bf16(a1, b1, acc_o[ds], 0, 0, 0);
        }

        #pragma unroll
        for (int sub = 0; sub < 4; ++sub)
            #pragma unroll
            for (int r = 0; r < 4; ++r)
                lvC[sub][r] = lvN[sub][r];
    }

    #pragma unroll
    for (int ds = 0; ds < 4; ++ds) {
        #pragma unroll
        for (int r = 0; r < 4; ++r) {
            const int tg = trow + r0 + r;
            atomicAdd(&out[(size_t)tg * DQK + ds * 16 + lo], acc_o[ds][r]);
        }
    }
}

extern "C" void kernel_launch(void* const* d_in, const int* in_sizes, int n_in,
                              void* d_out, int out_size, void* d_ws, size_t ws_size,
                              hipStream_t stream) {
    const float* x  = (const float*)d_in[0];
    const float* Wq = (const float*)d_in[1];
    const float* Wk = (const float*)d_in[2];
    const float* Wv = (const float*)d_in[3];
    const float* l  = (const float*)d_in[4];
    float* out = (float*)d_out;

    __hip_bfloat16* qb  = (__hip_bfloat16*)d_ws;
    __hip_bfloat16* kb  = qb + (size_t)TT * DQK;
    __hip_bfloat16* vt  = kb + (size_t)TT * DQK;
    __hip_bfloat16* wtb = vt + (size_t)TT * DQK;   // [3][64][512]

    zero_kernel<<<(out_size / 4 + 255) / 256, 256, 0, stream>>>(out, out_size / 4);
    wconv_kernel<<<dim3(DIN / 64, 3), 256, 0, stream>>>(Wq, Wk, Wv, wtb);
    proj_kernel<<<TT / 64, 256, 0, stream>>>(x, wtb, qb, kb, vt);
    attn_kernel<<<dim3(TT / TM, TT / SCHUNK), 512, 0, stream>>>(qb, kb, vt, l, out);
}

// Round 6
// 82.516 us; speedup vs baseline: 1.5491x; 1.5491x over previous
//
#include <hip/hip_runtime.h>
#include <hip/hip_bf16.h>

#define TT 8192
#define DIN 512
#define DQK 64

typedef __attribute__((ext_vector_type(8))) short short8;
typedef __attribute__((ext_vector_type(4))) float f32x4;

// ---------------- zero kernel ----------------
__global__ __launch_bounds__(256) void zero_kernel(float* __restrict__ out, int n4)
{
    int i = blockIdx.x * 256 + threadIdx.x;
    if (i < n4) ((f32x4*)out)[i] = (f32x4){0.f, 0.f, 0.f, 0.f};
}

// ---------------- Kernel 0: W [512][64] f32 -> WT bf16 [3][64][512] ----------------
__global__ __launch_bounds__(256) void wconv_kernel(
    const float* __restrict__ Wq, const float* __restrict__ Wk, const float* __restrict__ Wv,
    __hip_bfloat16* __restrict__ wtb)
{
    __shared__ float tile[64][65];
    const int m = blockIdx.y;
    const float* W = m == 0 ? Wq : (m == 1 ? Wk : Wv);
    const int k0 = blockIdx.x * 64;
    const int tid = threadIdx.x;

    {
        const int col4 = (tid & 15) * 4;
        #pragma unroll
        for (int it = 0; it < 4; ++it) {
            const int row = (tid >> 4) + it * 16;
            float4 v = *(const float4*)&W[(size_t)(k0 + row) * DQK + col4];
            tile[row][col4 + 0] = v.x; tile[row][col4 + 1] = v.y;
            tile[row][col4 + 2] = v.z; tile[row][col4 + 3] = v.w;
        }
    }
    __syncthreads();
    {
        const int d = tid >> 2;
        const int kc = (tid & 3) * 16;
        short tmp[16];
        #pragma unroll
        for (int j = 0; j < 16; ++j) {
            __hip_bfloat16 h = __float2bfloat16(tile[kc + j][d]);
            tmp[j] = *(short*)&h;
        }
        short* dst = (short*)wtb + ((size_t)m * 64 + d) * DIN + k0 + kc;
        *(short8*)dst       = *(short8*)&tmp[0];
        *(short8*)(dst + 8) = *(short8*)&tmp[8];
    }
}

// ---------------- Kernel 1: MFMA projections ----------------
#define PP 72

__global__ __launch_bounds__(256) void proj_kernel(
    const float* __restrict__ x,
    const __hip_bfloat16* __restrict__ wtb,
    __hip_bfloat16* __restrict__ qb, __hip_bfloat16* __restrict__ kb,
    __hip_bfloat16* __restrict__ vt)
{
    __shared__ short xb[64][PP];        // x tile [row][k]
    __shared__ short wb[3][64][PP];     // W^T tiles [m][col(d)][k]

    const int rowBase = blockIdx.x * 64;
    const int tid = threadIdx.x;
    const int lane = tid & 63;
    const int w = tid >> 6;
    const int lo = lane & 15, hi = lane >> 4;

    f32x4 acc[3][4];
    #pragma unroll
    for (int m = 0; m < 3; ++m)
        #pragma unroll
        for (int cf = 0; cf < 4; ++cf) acc[m][cf] = (f32x4){0.f, 0.f, 0.f, 0.f};

    for (int kk = 0; kk < DIN; kk += 64) {
        // stage x 64x64 -> bf16 (vectorized)
        {
            const int r = tid >> 2;
            const int c0 = (tid & 3) * 16;
            const float* xp = x + (size_t)(rowBase + r) * DIN + kk + c0;
            short tmp[16];
            #pragma unroll
            for (int j = 0; j < 16; j += 4) {
                float4 v = *(const float4*)(xp + j);
                __hip_bfloat16 h0 = __float2bfloat16(v.x);
                __hip_bfloat16 h1 = __float2bfloat16(v.y);
                __hip_bfloat16 h2 = __float2bfloat16(v.z);
                __hip_bfloat16 h3 = __float2bfloat16(v.w);
                tmp[j + 0] = *(short*)&h0; tmp[j + 1] = *(short*)&h1;
                tmp[j + 2] = *(short*)&h2; tmp[j + 3] = *(short*)&h3;
            }
            *(short8*)&xb[r][c0]     = *(short8*)&tmp[0];
            *(short8*)&xb[r][c0 + 8] = *(short8*)&tmp[8];
        }
        // stage W^T (already bf16, vector copy)
        {
            const int d = tid >> 2;
            const int kc = (tid & 3) * 16;
            #pragma unroll
            for (int m = 0; m < 3; ++m) {
                const short* src = (const short*)wtb + ((size_t)m * 64 + d) * DIN + kk + kc;
                *(short8*)&wb[m][d][kc]     = *(const short8*)src;
                *(short8*)&wb[m][d][kc + 8] = *(const short8*)(src + 8);
            }
        }
        __syncthreads();

        short8 a0 = *(short8*)&xb[w * 16 + lo][hi * 8];
        short8 a1 = *(short8*)&xb[w * 16 + lo][32 + hi * 8];
        #pragma unroll
        for (int m = 0; m < 3; ++m) {
            #pragma unroll
            for (int cf = 0; cf < 4; ++cf) {
                short8 b0 = *(short8*)&wb[m][cf * 16 + lo][hi * 8];
                short8 b1 = *(short8*)&wb[m][cf * 16 + lo][32 + hi * 8];
                acc[m][cf] = __builtin_amdgcn_mfma_f32_16x16x32_bf16(a0, b0, acc[m][cf], 0, 0, 0);
                acc[m][cf] = __builtin_amdgcn_mfma_f32_16x16x32_bf16(a1, b1, acc[m][cf], 0, 0, 0);
            }
        }
        __syncthreads();
    }

    #pragma unroll
    for (int cf = 0; cf < 4; ++cf) {
        #pragma unroll
        for (int r = 0; r < 4; ++r) {
            const int tg = rowBase + w * 16 + hi * 4 + r;
            const int d  = cf * 16 + lo;
            __hip_bfloat16 hq = __float2bfloat16(acc[0][cf][r]);
            __hip_bfloat16 hk = __float2bfloat16(acc[1][cf][r]);
            __hip_bfloat16 hv = __float2bfloat16(acc[2][cf][r]);
            qb[(size_t)tg * DQK + d] = hq;
            kb[(size_t)tg * DQK + d] = hk;
            vt[(size_t)d * TT + tg]  = hv;
        }
    }
}

// ---------------- Kernel 2: single-barrier double-buffered MFMA core ----------------
#define TM 128       // t rows per block (8 waves x 16)
#define TS 64        // s per step
#define SCHUNK 512   // s range per block (grid.y)
#define LP 72        // padded LDS row stride in shorts (144 B)

__global__ __launch_bounds__(512) void attn_kernel(
    const __hip_bfloat16* __restrict__ qb,
    const __hip_bfloat16* __restrict__ kb,
    const __hip_bfloat16* __restrict__ vt,
    const float* __restrict__ l,
    float* __restrict__ out)
{
    __shared__ short K_lds[2][TS][LP];   // K[s][k], double-buffered
    __shared__ short V_lds[2][DQK][LP];  // Vt[d][s_local], double-buffered
    __shared__ short S_lds[8][16][LP];   // wave-private S bounce

    const int t0 = blockIdx.x * TM;
    const int sStart = blockIdx.y * SCHUNK;
    if (sStart >= t0 + TM) return;
    const int sEnd = min(sStart + SCHUNK, t0 + TM);

    const int tid = threadIdx.x;
    const int lane = tid & 63;
    const int w = tid >> 6;
    const int lo = lane & 15, hi = lane >> 4;
    const int trow = t0 + w * 16;
    const int r0 = hi * 4;

    // staging assignment: one short8 per thread per matrix per tile
    const int srow = tid >> 3;          // 0..63
    const int sc8  = (tid & 7) * 8;

    short8 qf0, qf1;
    {
        const short* qp = (const short*)qb + (size_t)(trow + lo) * DQK;
        qf0 = *(const short8*)(qp + hi * 8);
        qf1 = *(const short8*)(qp + 32 + hi * 8);
    }

    f32x4 acc_o[4];
    #pragma unroll
    for (int i = 0; i < 4; ++i) acc_o[i] = (f32x4){0.f, 0.f, 0.f, 0.f};

    // ---- prologue: tile 0 into buf 0, l slice 0 into regs ----
    short8 kreg = *(const short8*)((const short*)kb + (size_t)(sStart + srow) * DQK + sc8);
    short8 vreg = *(const short8*)((const short*)vt + (size_t)srow * TT + sStart + sc8);

    float lvC[4][4];
    float lvN[4][4];
    {
        const bool act0 = (sStart <= trow + 15);
        #pragma unroll
        for (int sub = 0; sub < 4; ++sub) {
            const int s_glob = sStart + sub * 16 + lo;
            #pragma unroll
            for (int r = 0; r < 4; ++r) {
                const int tg = trow + r0 + r;
                lvC[sub][r] = (act0 && s_glob <= tg)
                    ? __builtin_nontemporal_load(&l[(size_t)tg * TT + s_glob]) : 0.f;
            }
        }
    }

    *(short8*)&K_lds[0][srow][sc8] = kreg;
    *(short8*)&V_lds[0][srow][sc8] = vreg;
    __syncthreads();

    int cur = 0;
    for (int s0 = sStart; s0 < sEnd; s0 += TS) {
        const int sN = s0 + TS;
        const bool havN = (sN < sEnd);

        // (1) issue K/V loads for tile n+1 (fly through this step's compute)
        if (havN) {
            kreg = *(const short8*)((const short*)kb + (size_t)(sN + srow) * DQK + sc8);
            vreg = *(const short8*)((const short*)vt + (size_t)srow * TT + sN + sc8);
        }

        // (2) issue l loads for step n+1
        const bool actN = havN && (sN <= trow + 15);
        if (actN) {
            if (sN + TS - 1 <= trow) {
                // full tile: no per-element mask
                #pragma unroll
                for (int sub = 0; sub < 4; ++sub) {
                    const int s_glob = sN + sub * 16 + lo;
                    #pragma unroll
                    for (int r = 0; r < 4; ++r) {
                        const int tg = trow + r0 + r;
                        lvN[sub][r] = __builtin_nontemporal_load(&l[(size_t)tg * TT + s_glob]);
                    }
                }
            } else {
                #pragma unroll
                for (int sub = 0; sub < 4; ++sub) {
                    const int s_glob = sN + sub * 16 + lo;
                    #pragma unroll
                    for (int r = 0; r < 4; ++r) {
                        const int tg = trow + r0 + r;
                        lvN[sub][r] = (s_glob <= tg)
                            ? __builtin_nontemporal_load(&l[(size_t)tg * TT + s_glob]) : 0.f;
                    }
                }
            }
        } else {
            #pragma unroll
            for (int sub = 0; sub < 4; ++sub)
                #pragma unroll
                for (int r = 0; r < 4; ++r) lvN[sub][r] = 0.f;
        }

        // (3) compute step n from LDS[cur]
        if (s0 <= trow + 15) {
            // QK^T -> *l -> bf16 -> S_lds (wave-private)
            #pragma unroll
            for (int sub = 0; sub < 4; ++sub) {
                f32x4 acc = (f32x4){0.f, 0.f, 0.f, 0.f};
                short8 b0 = *(short8*)&K_lds[cur][sub * 16 + lo][hi * 8];
                short8 b1 = *(short8*)&K_lds[cur][sub * 16 + lo][32 + hi * 8];
                acc = __builtin_amdgcn_mfma_f32_16x16x32_bf16(qf0, b0, acc, 0, 0, 0);
                acc = __builtin_amdgcn_mfma_f32_16x16x32_bf16(qf1, b1, acc, 0, 0, 0);
                #pragma unroll
                for (int r = 0; r < 4; ++r) {
                    float sv = acc[r] * lvC[sub][r];
                    __hip_bfloat16 h = __float2bfloat16(sv);
                    S_lds[w][r0 + r][sub * 16 + lo] = *(short*)&h;
                }
            }
            // PV
            short8 a0 = *(short8*)&S_lds[w][lo][hi * 8];
            short8 a1 = *(short8*)&S_lds[w][lo][32 + hi * 8];
            #pragma unroll
            for (int ds = 0; ds < 4; ++ds) {
                short8 b0 = *(short8*)&V_lds[cur][ds * 16 + lo][hi * 8];
                short8 b1 = *(short8*)&V_lds[cur][ds * 16 + lo][32 + hi * 8];
                acc_o[ds] = __builtin_amdgcn_mfma_f32_16x16x32_bf16(a0, b0, acc_o[ds], 0, 0, 0);
                acc_o[ds] = __builtin_amdgcn_mfma_f32_16x16x32_bf16(a1, b1, acc_o[ds], 0, 0, 0);
            }
        }

        // (4) write tile n+1 into the other buffer; single barrier per step
        if (havN) {
            *(short8*)&K_lds[cur ^ 1][srow][sc8] = kreg;
            *(short8*)&V_lds[cur ^ 1][srow][sc8] = vreg;
        }
        __syncthreads();
        cur ^= 1;

        #pragma unroll
        for (int sub = 0; sub < 4; ++sub)
            #pragma unroll
            for (int r = 0; r < 4; ++r)
                lvC[sub][r] = lvN[sub][r];
    }

    #pragma unroll
    for (int ds = 0; ds < 4; ++ds) {
        #pragma unroll
        for (int r = 0; r < 4; ++r) {
            const int tg = trow + r0 + r;
            atomicAdd(&out[(size_t)tg * DQK + ds * 16 + lo], acc_o[ds][r]);
        }
    }
}

extern "C" void kernel_launch(void* const* d_in, const int* in_sizes, int n_in,
                              void* d_out, int out_size, void* d_ws, size_t ws_size,
                              hipStream_t stream) {
    const float* x  = (const float*)d_in[0];
    const float* Wq = (const float*)d_in[1];
    const float* Wk = (const float*)d_in[2];
    const float* Wv = (const float*)d_in[3];
    const float* l  = (const float*)d_in[4];
    float* out = (float*)d_out;

    __hip_bfloat16* qb  = (__hip_bfloat16*)d_ws;
    __hip_bfloat16* kb  = qb + (size_t)TT * DQK;
    __hip_bfloat16* vt  = kb + (size_t)TT * DQK;
    __hip_bfloat16* wtb = vt + (size_t)TT * DQK;   // [3][64][512]

    zero_kernel<<<(out_size / 4 + 255) / 256, 256, 0, stream>>>(out, out_size / 4);
    wconv_kernel<<<dim3(DIN / 64, 3), 256, 0, stream>>>(Wq, Wk, Wv, wtb);
    proj_kernel<<<TT / 64, 256, 0, stream>>>(x, wtb, qb, kb, vt);
    attn_kernel<<<dim3(TT / TM, TT / SCHUNK), 512, 0, stream>>>(qb, kb, vt, l, out);
}